// Round 1
// baseline (315.548 us; speedup 1.0000x reference)
//
#include <hip/hip_runtime.h>
#include <math.h>

#define NB 16
#define NN 64
#define NF 64
#define NH 4
#define NR 50
#define NC 256

__device__ __forceinline__ float siluf(float x) { return x / (1.f + __expf(-x)); }

__device__ __forceinline__ float wave_max(float v) {
#pragma unroll
    for (int s = 32; s >= 1; s >>= 1) v = fmaxf(v, __shfl_xor(v, s));
    return v;
}
__device__ __forceinline__ float wave_sum(float v) {
#pragma unroll
    for (int s = 32; s >= 1; s >>= 1) v += __shfl_xor(v, s);
    return v;
}

// One block per (b,i). 256 threads.
__global__ __launch_bounds__(256)
void sake_fused_kernel(
    const float* __restrict__ h, const float* __restrict__ x, const float* __restrict__ v,
    const float* __restrict__ W_in, const float* __restrict__ b_in,
    const float* __restrict__ rbf_means, const float* __restrict__ rbf_betas,
    const float* __restrict__ W_e1, const float* __restrict__ b_e1,
    const float* __restrict__ W_e2, const float* __restrict__ b_e2,
    const float* __restrict__ W_sem, const float* __restrict__ b_sem,
    const float* __restrict__ log_gamma,
    const float* __restrict__ W_xmix,
    const float* __restrict__ W_post1, const float* __restrict__ b_post1,
    const float* __restrict__ W_post2, const float* __restrict__ b_post2,
    const float* __restrict__ W_node1, const float* __restrict__ b_node1,
    const float* __restrict__ W_node2, const float* __restrict__ b_node2,
    const float* __restrict__ W_vel1, const float* __restrict__ b_vel1,
    const float* __restrict__ W_vel2, const float* __restrict__ W_vmix,
    float* __restrict__ out_h, float* __restrict__ out_x, float* __restrict__ out_v)
{
    const int bi = blockIdx.x;      // 0..1023
    const int b  = bi >> 6;
    const int i  = bi & 63;
    const int t  = threadIdx.x;

    // LDS. s_h is reused as s_he (h_e) after phase 3.
    __shared__ float s_h[64 * 65];      // h rows of this batch; later h_e
    __shared__ float s_u[64 * 65];      // silu(he_in @ W_e1)
    __shared__ float s_rbfh[64 * 52];   // rbf * h_mid
    __shared__ float s_xhat[64 * 4];    // xhat.x,y,z, d
    __shared__ float s_hi[64];
    __shared__ float s_midi[64];        // hi-part of h_mid (+b_in), 50 used
    __shared__ float s_uc[64];          // hi-part of W_e1 (+b_e1)
    __shared__ float s_att[64 * 4];     // att[j][h]
    __shared__ float s_hagg[256];
    __shared__ float s_comb[256 * 3];   // comb_sum (mean over j)
    __shared__ float s_hcp[256];        // |comb_sum|^2 per c
    __shared__ float s_sm[64 * 5 + 8];  // p1 | hcomb | n1 | hout | v1 | gate,dv

    const float* hb = h + b * NN * NF;

    // ---------- Phase 0: load h rows, hi, geometry ----------
    for (int idx = t; idx < 64 * 16; idx += 256) {
        int j = idx >> 4, q = idx & 15;
        float4 val = ((const float4*)(hb + j * 64))[q];
        float* dst = &s_h[j * 65 + q * 4];
        dst[0] = val.x; dst[1] = val.y; dst[2] = val.z; dst[3] = val.w;
    }
    if (t < 64) s_hi[t] = hb[i * 64 + t];
    if (t < 64) {
        int j = t;
        float dx = x[(b * NN + j) * 3 + 0] - x[(b * NN + i) * 3 + 0];
        float dy = x[(b * NN + j) * 3 + 1] - x[(b * NN + i) * 3 + 1];
        float dz = x[(b * NN + j) * 3 + 2] - x[(b * NN + i) * 3 + 2];
        float d2 = dx * dx + dy * dy + dz * dz;
        float d  = sqrtf(fmaxf(d2, 0.f) + 1e-5f);
        float inv = 1.f / (d + 1e-5f);
        s_xhat[j * 4 + 0] = dx * inv;
        s_xhat[j * 4 + 1] = dy * inv;
        s_xhat[j * 4 + 2] = dz * inv;
        s_xhat[j * 4 + 3] = d;
    }
    __syncthreads();

    // ---------- Phase 0.5: j-invariant (h_i) partial sums ----------
    if (t < 50) {
        float acc = b_in[t];
#pragma unroll 8
        for (int k = 0; k < 64; k++) acc += s_hi[k] * W_in[(64 + k) * NR + t];
        s_midi[t] = acc;
    } else if (t >= 64 && t < 128) {
        int f = t - 64;
        float acc = b_e1[f];
#pragma unroll 8
        for (int k = 0; k < 64; k++) acc += s_hi[k] * W_e1[(64 + k) * NF + f];
        s_uc[f] = acc;
    }
    __syncthreads();

    // ---------- Phase 1: h_mid (hj part) + RBF -> rbf*h_mid ----------
    {
        int j = t >> 2, p = t & 3;
        float d = s_xhat[j * 4 + 3];
        float cut = 0.5f * (__cosf(d * 0.6283185307179586f) + 1.f) * (d < 5.f ? 1.f : 0.f);
        float emd = __expf(-d);
        for (int r = p; r < 50; r += 4) {
            float acc = s_midi[r];
#pragma unroll 8
            for (int k = 0; k < 64; k++) acc += s_h[j * 65 + k] * W_in[k * NR + r];
            float df = emd - rbf_means[r];
            float rbf = cut * __expf(-rbf_betas[r] * df * df);
            s_rbfh[j * 52 + r] = rbf * acc;
        }
    }
    __syncthreads();

    // ---------- Phase 2: u = silu(he_in @ W_e1 + b_e1) ----------
    {
        int f = t & 63, jo = t >> 6;
        for (int jg = 0; jg < 16; jg++) {
            int j = jg * 4 + jo;
            float acc = s_uc[f];
#pragma unroll 8
            for (int k = 0; k < 64; k++) acc += s_h[j * 65 + k] * W_e1[k * NF + f];
#pragma unroll 5
            for (int r = 0; r < 50; r++) acc += s_rbfh[j * 52 + r] * W_e1[(128 + r) * NF + f];
            acc += s_xhat[j * 4 + 3] * W_e1[178 * NF + f];
            s_u[j * 65 + f] = siluf(acc);
        }
    }
    __syncthreads();

    // ---------- Phase 3: h_e = u @ W_e2 + b_e2 (into s_h) ----------
    {
        int f = t & 63, jo = t >> 6;
        for (int jg = 0; jg < 16; jg++) {
            int j = jg * 4 + jo;
            float acc = b_e2[f];
#pragma unroll 8
            for (int k = 0; k < 64; k++) acc += s_u[j * 65 + k] * W_e2[k * NF + f];
            s_h[j * 65 + f] = acc;   // s_h now holds h_e
        }
    }
    __syncthreads();

    // ---------- Phase 4: sem/euc softmax over j, att ----------
    {
        int hh = t >> 6;   // wave id = head
        int j  = t & 63;   // lane = neighbor
        float acc = b_sem[hh];
#pragma unroll 8
        for (int f = 0; f < 64; f++) acc += s_h[j * 65 + f] * W_sem[f * NH + hh];
        // celu(alpha=2)
        float cel = fmaxf(acc, 0.f) + fminf(0.f, 2.f * (__expf(0.5f * acc) - 1.f));
        float diag = (j == i) ? 1e5f : 0.f;
        float slog = cel - diag;
        float m1 = wave_max(slog);
        float e1 = __expf(slog - m1);
        float sem = e1 / wave_sum(e1);
        float gam = __expf(log_gamma[hh]);
        float elog = -(s_xhat[j * 4 + 3] + diag) * gam;
        float m2 = wave_max(elog);
        float e2 = __expf(elog - m2);
        float euc = e2 / wave_sum(e2);
        float a = sem * euc;
        a = a / wave_sum(a);
        s_att[j * 4 + hh] = a;
    }
    __syncthreads();

    // ---------- Phase 5: h_agg[c] = sum_j h_e[j][f]*att[j][h] ----------
    {
        int f = t >> 2, hh = t & 3;
        float acc = 0.f;
#pragma unroll 8
        for (int j = 0; j < 64; j++) acc += s_h[j * 65 + f] * s_att[j * 4 + hh];
        s_hagg[t] = acc;
    }

    // ---------- Phase 6: coeff = tanh(hea @ W_xmix); comb_sum; (reg-tiled GEMM) ----------
    {
        int tc = t >> 4;          // 0..15 -> c'0 = 16*tc
        int tj = t & 15;          // j0 = 4*tj
        int c0 = tc * 16, j0 = tj * 4;

        float attr[4][4];
#pragma unroll
        for (int jj = 0; jj < 4; jj++)
#pragma unroll
            for (int hh = 0; hh < 4; hh++) attr[jj][hh] = s_att[(j0 + jj) * 4 + hh];

        float acc[4][16];
#pragma unroll
        for (int jj = 0; jj < 4; jj++)
#pragma unroll
            for (int cc = 0; cc < 16; cc++) acc[jj][cc] = 0.f;

        for (int f = 0; f < 64; f++) {
            float he4[4];
#pragma unroll
            for (int jj = 0; jj < 4; jj++) he4[jj] = s_h[(j0 + jj) * 65 + f];
#pragma unroll
            for (int hh = 0; hh < 4; hh++) {
                int c = f * 4 + hh;
                const float4* wr = (const float4*)(W_xmix + c * 256 + c0);
                float4 w0 = wr[0], w1 = wr[1], w2 = wr[2], w3 = wr[3];
                float w[16] = { w0.x, w0.y, w0.z, w0.w, w1.x, w1.y, w1.z, w1.w,
                                w2.x, w2.y, w2.z, w2.w, w3.x, w3.y, w3.z, w3.w };
#pragma unroll
                for (int jj = 0; jj < 4; jj++) {
                    float tv = he4[jj] * attr[jj][hh];
#pragma unroll
                    for (int cc = 0; cc < 16; cc++) acc[jj][cc] += tv * w[cc];
                }
            }
        }
        // tanh + partial comb_sum over this thread's 4 j's
        float xh[4][3];
#pragma unroll
        for (int jj = 0; jj < 4; jj++)
#pragma unroll
            for (int k = 0; k < 3; k++) xh[jj][k] = s_xhat[(j0 + jj) * 4 + k];

        float p[16][3];
#pragma unroll
        for (int cc = 0; cc < 16; cc++)
#pragma unroll
            for (int k = 0; k < 3; k++) p[cc][k] = 0.f;

#pragma unroll
        for (int jj = 0; jj < 4; jj++) {
#pragma unroll
            for (int cc = 0; cc < 16; cc++) {
                float y = acc[jj][cc];
                float th = 1.f - 2.f / (__expf(2.f * y) + 1.f);   // tanh
#pragma unroll
                for (int k = 0; k < 3; k++) p[cc][k] += xh[jj][k] * th;
            }
        }
        // reduce over the 16 tj lanes (consecutive lanes within wave)
#pragma unroll
        for (int cc = 0; cc < 16; cc++) {
#pragma unroll
            for (int k = 0; k < 3; k++) {
                float val = p[cc][k];
                val += __shfl_down(val, 8, 16);
                val += __shfl_down(val, 4, 16);
                val += __shfl_down(val, 2, 16);
                val += __shfl_down(val, 1, 16);
                if (tj == 0) s_comb[(c0 + cc) * 3 + k] = val * (1.f / 64.f);
            }
        }
    }
    __syncthreads();

    // ---------- Phase 7: per-node MLPs ----------
    // h_comb_pre
    {
        float c0_ = s_comb[t * 3 + 0], c1_ = s_comb[t * 3 + 1], c2_ = s_comb[t * 3 + 2];
        s_hcp[t] = c0_ * c0_ + c1_ * c1_ + c2_ * c2_;
    }
    __syncthreads();
    if (t < 64) {  // post1
        float acc = b_post1[t];
#pragma unroll 8
        for (int c = 0; c < 256; c++) acc += s_hcp[c] * W_post1[c * NF + t];
        s_sm[0 + t] = siluf(acc);
    }
    __syncthreads();
    if (t < 64) {  // post2 -> h_comb
        float acc = b_post2[t];
#pragma unroll 8
        for (int k = 0; k < 64; k++) acc += s_sm[0 + k] * W_post2[k * NF + t];
        s_sm[64 + t] = siluf(acc);
    }
    __syncthreads();
    if (t < 64) {  // node1
        float acc = b_node1[t];
#pragma unroll 8
        for (int k = 0; k < 64; k++)  acc += s_hi[k] * W_node1[k * NF + t];
#pragma unroll 8
        for (int k = 0; k < 256; k++) acc += s_hagg[k] * W_node1[(64 + k) * NF + t];
#pragma unroll 8
        for (int k = 0; k < 64; k++)  acc += s_sm[64 + k] * W_node1[(320 + k) * NF + t];
        s_sm[128 + t] = siluf(acc);
    }
    __syncthreads();
    if (t < 64) {  // node2 + residual -> h_out
        float acc = b_node2[t];
#pragma unroll 8
        for (int k = 0; k < 64; k++) acc += s_sm[128 + k] * W_node2[k * NF + t];
        float ho = s_hi[t] + siluf(acc);
        s_sm[192 + t] = ho;
        out_h[(b * NN + i) * NF + t] = ho;
    }
    __syncthreads();
    if (t < 64) {  // vel1
        float acc = b_vel1[t];
#pragma unroll 8
        for (int k = 0; k < 64; k++) acc += s_sm[192 + k] * W_vel1[k * NF + t];
        s_sm[256 + t] = siluf(acc);
    }
    __syncthreads();
    {
        int w = t >> 6, lane = t & 63;
        if (w == 0) {          // gate
            float pv = s_sm[256 + lane] * W_vel2[lane];
            float g = wave_sum(pv);
            if (lane == 0) s_sm[320] = 2.f / (1.f + __expf(-g));
        } else if (w <= 3) {   // delta_v[k], k = w-1
            int k = w - 1;
            float pv = 0.f;
#pragma unroll
            for (int q = 0; q < 4; q++) {
                int c = lane + 64 * q;
                pv += s_comb[c * 3 + k] * W_vmix[c];
            }
            float dv = wave_sum(pv);
            if (lane == 0) s_sm[321 + k] = dv;
        }
    }
    __syncthreads();
    if (t < 3) {
        float vout = s_sm[321 + t] + s_sm[320] * v[(b * NN + i) * 3 + t];
        out_v[(b * NN + i) * 3 + t] = vout;
        out_x[(b * NN + i) * 3 + t] = x[(b * NN + i) * 3 + t] + vout;
    }
}

extern "C" void kernel_launch(void* const* d_in, const int* in_sizes, int n_in,
                              void* d_out, int out_size, void* d_ws, size_t ws_size,
                              hipStream_t stream) {
    const float* h        = (const float*)d_in[0];
    const float* x        = (const float*)d_in[1];
    const float* v        = (const float*)d_in[2];
    const float* W_in     = (const float*)d_in[3];
    const float* b_in     = (const float*)d_in[4];
    const float* rbf_m    = (const float*)d_in[5];
    const float* rbf_b    = (const float*)d_in[6];
    const float* W_e1     = (const float*)d_in[7];
    const float* b_e1     = (const float*)d_in[8];
    const float* W_e2     = (const float*)d_in[9];
    const float* b_e2     = (const float*)d_in[10];
    const float* W_sem    = (const float*)d_in[11];
    const float* b_sem    = (const float*)d_in[12];
    const float* log_g    = (const float*)d_in[13];
    const float* W_xmix   = (const float*)d_in[14];
    const float* W_post1  = (const float*)d_in[15];
    const float* b_post1  = (const float*)d_in[16];
    const float* W_post2  = (const float*)d_in[17];
    const float* b_post2  = (const float*)d_in[18];
    const float* W_node1  = (const float*)d_in[19];
    const float* b_node1  = (const float*)d_in[20];
    const float* W_node2  = (const float*)d_in[21];
    const float* b_node2  = (const float*)d_in[22];
    const float* W_vel1   = (const float*)d_in[23];
    const float* b_vel1   = (const float*)d_in[24];
    const float* W_vel2   = (const float*)d_in[25];
    const float* W_vmix   = (const float*)d_in[26];

    float* out   = (float*)d_out;
    float* out_h = out;
    float* out_x = out + NB * NN * NF;
    float* out_v = out + NB * NN * NF + NB * NN * 3;

    sake_fused_kernel<<<NB * NN, 256, 0, stream>>>(
        h, x, v, W_in, b_in, rbf_m, rbf_b, W_e1, b_e1, W_e2, b_e2,
        W_sem, b_sem, log_g, W_xmix, W_post1, b_post1, W_post2, b_post2,
        W_node1, b_node1, W_node2, b_node2, W_vel1, b_vel1, W_vel2, W_vmix,
        out_h, out_x, out_v);
}

// Round 2
// 103.195 us; speedup vs baseline: 3.0578x; 3.0578x over previous
//
#include <hip/hip_runtime.h>
#include <math.h>

#define NB 16
#define NN 64
#define NF 64
#define NH 4
#define NR 50
#define NC 256

typedef __attribute__((ext_vector_type(8))) short short8;
typedef __attribute__((ext_vector_type(4))) float f32x4;

// d_ws layout (shorts): W_e1 pack (4nt*6ks*4g*16cl=1536 slots), W_e2 pack (512), W_xmix pack (8192)
#define WS_WE1 0
#define WS_WE2 (1536 * 8)
#define WS_WX  (2048 * 8)

__device__ __forceinline__ float siluf(float x) { return x / (1.f + __expf(-x)); }
__device__ __forceinline__ float tanhfast(float x) { return 1.f - 2.f / (__expf(2.f * x) + 1.f); }

__device__ __forceinline__ ushort f2bf(float f) {
    union { float f; unsigned u; } v; v.f = f;
    unsigned u = v.u;
    return (ushort)((u + 0x7FFFu + ((u >> 16) & 1u)) >> 16);  // RNE
}

__device__ __forceinline__ float wave_max(float v) {
#pragma unroll
    for (int s = 32; s >= 1; s >>= 1) v = fmaxf(v, __shfl_xor(v, s));
    return v;
}
__device__ __forceinline__ float wave_sum(float v) {
#pragma unroll
    for (int s = 32; s >= 1; s >>= 1) v += __shfl_xor(v, s);
    return v;
}

// ---- prep: pack weights to bf16 fragment-major layout (one 16B slot per thread) ----
__global__ __launch_bounds__(256)
void pack_weights(const float* __restrict__ W_e1, const float* __restrict__ W_e2,
                  const float* __restrict__ W_xmix, short* __restrict__ ws)
{
    int s = blockIdx.x * 256 + threadIdx.x;   // 0..10239
    short8 val;
    if (s < 1536) {               // W_e1: K=192 (179 real), N=64
        int cl = s & 15, g = (s >> 4) & 3, q = s >> 6;
        int ks = q % 6, nt = q / 6;
        int c = nt * 16 + cl, k0 = 32 * ks + 8 * g;
#pragma unroll
        for (int i = 0; i < 8; i++) {
            int k = k0 + i;
            float f = (k < 179) ? W_e1[k * NF + c] : 0.f;
            val[i] = (short)f2bf(f);
        }
        *(short8*)(&ws[WS_WE1 + s * 8]) = val;
    } else if (s < 2048) {        // W_e2: K=64, N=64
        int t = s - 1536;
        int cl = t & 15, g = (t >> 4) & 3, q = t >> 6;
        int ks = q & 1, nt = q >> 1;
        int c = nt * 16 + cl, k0 = 32 * ks + 8 * g;
#pragma unroll
        for (int i = 0; i < 8; i++) val[i] = (short)f2bf(W_e2[(k0 + i) * NF + c]);
        *(short8*)(&ws[WS_WE2 + t * 8]) = val;
    } else {                      // W_xmix: K=256, N=256
        int t = s - 2048;
        int cl = t & 15, g = (t >> 4) & 3, q = t >> 6;
        int ks = q & 7, wn = q >> 3;
        int c = (wn >> 2) * 64 + (wn & 3) * 16 + cl, k0 = 32 * ks + 8 * g;
#pragma unroll
        for (int i = 0; i < 8; i++) val[i] = (short)f2bf(W_xmix[(k0 + i) * NC + c]);
        *(short8*)(&ws[WS_WX + t * 8]) = val;
    }
}

// One block per (b,i). 256 threads = 4 waves.
__global__ __launch_bounds__(256)
void sake_fused_kernel(
    const float* __restrict__ h, const float* __restrict__ x, const float* __restrict__ v,
    const float* __restrict__ W_in, const float* __restrict__ b_in,
    const float* __restrict__ rbf_means, const float* __restrict__ rbf_betas,
    const float* __restrict__ b_e1, const float* __restrict__ b_e2,
    const float* __restrict__ W_sem, const float* __restrict__ b_sem,
    const float* __restrict__ log_gamma,
    const float* __restrict__ W_post1, const float* __restrict__ b_post1,
    const float* __restrict__ W_post2, const float* __restrict__ b_post2,
    const float* __restrict__ W_node1, const float* __restrict__ b_node1,
    const float* __restrict__ W_node2, const float* __restrict__ b_node2,
    const float* __restrict__ W_vel1, const float* __restrict__ b_vel1,
    const float* __restrict__ W_vel2, const float* __restrict__ W_vmix,
    const short* __restrict__ wpack,
    float* __restrict__ out_h, float* __restrict__ out_x, float* __restrict__ out_v)
{
    const int bi = blockIdx.x;
    const int b  = bi >> 6;
    const int i  = bi & 63;
    const int t  = threadIdx.x;
    const int w  = t >> 6, l = t & 63, lr = l & 15, lg = l >> 4;

    __shared__ float s_h[64 * 65];               // h rows, then h_e rows (f32)
    __shared__ __align__(16) short s_A[32 * 64 * 8];  // bf16 A staging, fragment-major [slot][j][8]
    __shared__ float s_xhat[64 * 4];
    __shared__ float s_hi[64];
    __shared__ float s_midi[64];
    __shared__ float s_att[64 * 4];
    __shared__ float s_hagg[256];
    __shared__ float s_comb[256 * 3];
    __shared__ float s_hcp[256];
    __shared__ float s_sm[64 * 5 + 8];

    const float* hb = h + b * NN * NF;
    const short8* A8  = (const short8*)s_A;
    short8*       A8w = (short8*)s_A;
    const short8* We1p = (const short8*)(wpack + WS_WE1);
    const short8* We2p = (const short8*)(wpack + WS_WE2);
    const short8* Wxp  = (const short8*)(wpack + WS_WX);

    // ---------- P0: load h rows, hi, geometry ----------
    for (int idx = t; idx < 64 * 16; idx += 256) {
        int j = idx >> 4, q = idx & 15;
        float4 val = ((const float4*)(hb + j * 64))[q];
        float* dst = &s_h[j * 65 + q * 4];
        dst[0] = val.x; dst[1] = val.y; dst[2] = val.z; dst[3] = val.w;
    }
    if (t < 64) s_hi[t] = hb[i * 64 + t];
    if (t < 64) {
        int j = t;
        float dx = x[(b * NN + j) * 3 + 0] - x[(b * NN + i) * 3 + 0];
        float dy = x[(b * NN + j) * 3 + 1] - x[(b * NN + i) * 3 + 1];
        float dz = x[(b * NN + j) * 3 + 2] - x[(b * NN + i) * 3 + 2];
        float d2 = dx * dx + dy * dy + dz * dz;
        float d  = sqrtf(fmaxf(d2, 0.f) + 1e-5f);
        float inv = 1.f / (d + 1e-5f);
        s_xhat[j * 4 + 0] = dx * inv;
        s_xhat[j * 4 + 1] = dy * inv;
        s_xhat[j * 4 + 2] = dz * inv;
        s_xhat[j * 4 + 3] = d;
    }
    __syncthreads();

    // ---------- P0.5: h_i part of h_mid (+b_in) ----------
    if (t < 50) {
        float acc = b_in[t];
#pragma unroll 8
        for (int k = 0; k < 64; k++) acc += s_hi[k] * W_in[(64 + k) * NR + t];
        s_midi[t] = acc;
    }
    __syncthreads();

    // ---------- P1: build A (bf16, fragment-major). slots 0..15: [h_j|h_i]; 16..23: rbf*h_mid|d|0 ----------
    {
        int j = t & 63, p = t >> 6;
        // h_cat slots
#pragma unroll
        for (int q = 0; q < 4; q++) {
            int sl = 4 * p + q;
            short8 val;
#pragma unroll
            for (int e = 0; e < 8; e++) {
                int k = sl * 8 + e;
                float f = (k < 64) ? s_h[j * 65 + k] : s_hi[k - 64];
                val[e] = (short)f2bf(f);
            }
            A8w[sl * 64 + j] = val;
        }
        // rbf slots
        float d = s_xhat[j * 4 + 3];
        float cut = 0.5f * (__cosf(d * 0.6283185307179586f) + 1.f) * (d < 5.f ? 1.f : 0.f);
        float emd = __expf(-d);
#pragma unroll
        for (int half = 0; half < 2; half++) {
            int sl = 16 + 2 * p + half;
            short8 val;
            for (int e = 0; e < 8; e++) {
                int k = sl * 8 + e;
                float outv;
                if (k < 178) {
                    int r = k - 128;
                    float m = s_midi[r];
#pragma unroll 8
                    for (int kk = 0; kk < 64; kk++) m += s_h[j * 65 + kk] * W_in[kk * NR + r];
                    float df = emd - rbf_means[r];
                    outv = cut * __expf(-rbf_betas[r] * df * df) * m;
                } else if (k == 178) outv = d;
                else outv = 0.f;
                val[e] = (short)f2bf(outv);
            }
            A8w[sl * 64 + j] = val;
        }
    }
    __syncthreads();

    // ---------- P2 (MFMA): u = silu(A @ W_e1 + b_e1), written back to A slots 0..7 (bf16) ----------
    {
        f32x4 acc[4];
#pragma unroll
        for (int jt = 0; jt < 4; jt++) { acc[jt][0] = 0.f; acc[jt][1] = 0.f; acc[jt][2] = 0.f; acc[jt][3] = 0.f; }
        for (int ks = 0; ks < 6; ks++) {
            short8 bb = We1p[(w * 6 + ks) * 64 + l];
#pragma unroll
            for (int jt = 0; jt < 4; jt++) {
                short8 aa = A8[(ks * 4 + lg) * 64 + jt * 16 + lr];
                acc[jt] = __builtin_amdgcn_mfma_f32_16x16x32_bf16(aa, bb, acc[jt], 0, 0, 0);
            }
        }
        __syncthreads();   // all A reads done before overwrite
        float be = b_e1[w * 16 + lr];
        int f = w * 16 + lr;
#pragma unroll
        for (int jt = 0; jt < 4; jt++)
#pragma unroll
            for (int r = 0; r < 4; r++) {
                int j = jt * 16 + lg * 4 + r;
                s_A[((f >> 3) * 64 + j) * 8 + (f & 7)] = (short)f2bf(siluf(acc[jt][r] + be));
            }
        __syncthreads();
    }

    // ---------- P3 (MFMA): h_e = u @ W_e2 + b_e2 -> s_h (f32) ----------
    {
        f32x4 acc[4];
#pragma unroll
        for (int jt = 0; jt < 4; jt++) { acc[jt][0] = 0.f; acc[jt][1] = 0.f; acc[jt][2] = 0.f; acc[jt][3] = 0.f; }
#pragma unroll
        for (int ks = 0; ks < 2; ks++) {
            short8 bb = We2p[(w * 2 + ks) * 64 + l];
#pragma unroll
            for (int jt = 0; jt < 4; jt++) {
                short8 aa = A8[(ks * 4 + lg) * 64 + jt * 16 + lr];
                acc[jt] = __builtin_amdgcn_mfma_f32_16x16x32_bf16(aa, bb, acc[jt], 0, 0, 0);
            }
        }
        float be2 = b_e2[w * 16 + lr];
        int f = w * 16 + lr;
#pragma unroll
        for (int jt = 0; jt < 4; jt++)
#pragma unroll
            for (int r = 0; r < 4; r++) {
                int j = jt * 16 + lg * 4 + r;
                s_h[j * 65 + f] = acc[jt][r] + be2;   // s_h now holds h_e
            }
        __syncthreads();
    }

    // ---------- P4: sem/euc softmax over j, att ----------
    {
        int hh = w;        // wave = head
        int j  = l;        // lane = neighbor
        float acc = b_sem[hh];
#pragma unroll 8
        for (int f = 0; f < 64; f++) acc += s_h[j * 65 + f] * W_sem[f * NH + hh];
        float cel = fmaxf(acc, 0.f) + fminf(0.f, 2.f * (__expf(0.5f * acc) - 1.f));
        float diag = (j == i) ? 1e5f : 0.f;
        float slog = cel - diag;
        float m1 = wave_max(slog);
        float e1 = __expf(slog - m1);
        float sem = e1 / wave_sum(e1);
        float gam = __expf(log_gamma[hh]);
        float elog = -(s_xhat[j * 4 + 3] + diag) * gam;
        float m2 = wave_max(elog);
        float e2 = __expf(elog - m2);
        float euc = e2 / wave_sum(e2);
        float a = sem * euc;
        a = a / wave_sum(a);
        s_att[j * 4 + hh] = a;
    }
    __syncthreads();

    // ---------- P5: h_agg[c] = sum_j h_e[j][f]*att[j][h] ----------
    {
        int f = t >> 2, hh = t & 3;
        float acc = 0.f;
#pragma unroll 8
        for (int j = 0; j < 64; j++) acc += s_h[j * 65 + f] * s_att[j * 4 + hh];
        s_hagg[t] = acc;
    }

    // ---------- P5.5: build hea (A for xmix GEMM) in bf16 fragment-major, slots 0..31 ----------
    {
        int j = t & 63, kc = t >> 6;
        float att0 = s_att[j * 4 + 0], att1 = s_att[j * 4 + 1];
        float att2 = s_att[j * 4 + 2], att3 = s_att[j * 4 + 3];
        float attv[4] = { att0, att1, att2, att3 };
#pragma unroll
        for (int ss = 0; ss < 8; ss++) {
            int sl = kc * 8 + ss;      // slot covers k = 8*sl .. +8
            short8 val;
#pragma unroll
            for (int e = 0; e < 8; e++) {
                int k = sl * 8 + e;
                float he = s_h[j * 65 + (k >> 2)];
                val[e] = (short)f2bf(he * attv[k & 3]);
            }
            A8w[sl * 64 + j] = val;
        }
    }
    __syncthreads();

    // ---------- P6 (MFMA): coeff = tanh(hea @ W_xmix); comb_sum over j ----------
    {
        f32x4 acc[4][4];
#pragma unroll
        for (int jt = 0; jt < 4; jt++)
#pragma unroll
            for (int nt = 0; nt < 4; nt++) { acc[jt][nt][0] = 0.f; acc[jt][nt][1] = 0.f; acc[jt][nt][2] = 0.f; acc[jt][nt][3] = 0.f; }

        for (int ks = 0; ks < 8; ks++) {
            short8 aa[4], bb[4];
#pragma unroll
            for (int jt = 0; jt < 4; jt++) aa[jt] = A8[(ks * 4 + lg) * 64 + jt * 16 + lr];
#pragma unroll
            for (int nt = 0; nt < 4; nt++) bb[nt] = Wxp[((w * 4 + nt) * 8 + ks) * 64 + l];
#pragma unroll
            for (int jt = 0; jt < 4; jt++)
#pragma unroll
                for (int nt = 0; nt < 4; nt++)
                    acc[jt][nt] = __builtin_amdgcn_mfma_f32_16x16x32_bf16(aa[jt], bb[nt], acc[jt][nt], 0, 0, 0);
        }
        // epilogue: tanh, weight by x_hat, reduce over j
#pragma unroll
        for (int nt = 0; nt < 4; nt++) {
            float p0 = 0.f, p1 = 0.f, p2 = 0.f;
#pragma unroll
            for (int jt = 0; jt < 4; jt++)
#pragma unroll
                for (int r = 0; r < 4; r++) {
                    int j = jt * 16 + lg * 4 + r;
                    float th = tanhfast(acc[jt][nt][r]);
                    p0 += s_xhat[j * 4 + 0] * th;
                    p1 += s_xhat[j * 4 + 1] * th;
                    p2 += s_xhat[j * 4 + 2] * th;
                }
            p0 += __shfl_xor(p0, 16); p0 += __shfl_xor(p0, 32);
            p1 += __shfl_xor(p1, 16); p1 += __shfl_xor(p1, 32);
            p2 += __shfl_xor(p2, 16); p2 += __shfl_xor(p2, 32);
            if (lg == 0) {
                int c = w * 64 + nt * 16 + lr;
                s_comb[c * 3 + 0] = p0 * (1.f / 64.f);
                s_comb[c * 3 + 1] = p1 * (1.f / 64.f);
                s_comb[c * 3 + 2] = p2 * (1.f / 64.f);
            }
        }
    }
    __syncthreads();

    // ---------- P7: per-node MLPs ----------
    {
        float c0_ = s_comb[t * 3 + 0], c1_ = s_comb[t * 3 + 1], c2_ = s_comb[t * 3 + 2];
        s_hcp[t] = c0_ * c0_ + c1_ * c1_ + c2_ * c2_;
    }
    __syncthreads();
    if (t < 64) {
        float acc = b_post1[t];
#pragma unroll 8
        for (int c = 0; c < 256; c++) acc += s_hcp[c] * W_post1[c * NF + t];
        s_sm[0 + t] = siluf(acc);
    }
    __syncthreads();
    if (t < 64) {
        float acc = b_post2[t];
#pragma unroll 8
        for (int k = 0; k < 64; k++) acc += s_sm[0 + k] * W_post2[k * NF + t];
        s_sm[64 + t] = siluf(acc);
    }
    __syncthreads();
    if (t < 64) {
        float acc = b_node1[t];
#pragma unroll 8
        for (int k = 0; k < 64; k++)  acc += s_hi[k] * W_node1[k * NF + t];
#pragma unroll 8
        for (int k = 0; k < 256; k++) acc += s_hagg[k] * W_node1[(64 + k) * NF + t];
#pragma unroll 8
        for (int k = 0; k < 64; k++)  acc += s_sm[64 + k] * W_node1[(320 + k) * NF + t];
        s_sm[128 + t] = siluf(acc);
    }
    __syncthreads();
    if (t < 64) {
        float acc = b_node2[t];
#pragma unroll 8
        for (int k = 0; k < 64; k++) acc += s_sm[128 + k] * W_node2[k * NF + t];
        float ho = s_hi[t] + siluf(acc);
        s_sm[192 + t] = ho;
        out_h[(b * NN + i) * NF + t] = ho;
    }
    __syncthreads();
    if (t < 64) {
        float acc = b_vel1[t];
#pragma unroll 8
        for (int k = 0; k < 64; k++) acc += s_sm[192 + k] * W_vel1[k * NF + t];
        s_sm[256 + t] = siluf(acc);
    }
    __syncthreads();
    {
        int lane = t & 63;
        if (w == 0) {
            float pv = s_sm[256 + lane] * W_vel2[lane];
            float g = wave_sum(pv);
            if (lane == 0) s_sm[320] = 2.f / (1.f + __expf(-g));
        } else if (w <= 3) {
            int k = w - 1;
            float pv = 0.f;
#pragma unroll
            for (int q = 0; q < 4; q++) {
                int c = lane + 64 * q;
                pv += s_comb[c * 3 + k] * W_vmix[c];
            }
            float dv = wave_sum(pv);
            if (lane == 0) s_sm[321 + k] = dv;
        }
    }
    __syncthreads();
    if (t < 3) {
        float vout = s_sm[321 + t] + s_sm[320] * v[(b * NN + i) * 3 + t];
        out_v[(b * NN + i) * 3 + t] = vout;
        out_x[(b * NN + i) * 3 + t] = x[(b * NN + i) * 3 + t] + vout;
    }
}

extern "C" void kernel_launch(void* const* d_in, const int* in_sizes, int n_in,
                              void* d_out, int out_size, void* d_ws, size_t ws_size,
                              hipStream_t stream) {
    const float* h        = (const float*)d_in[0];
    const float* x        = (const float*)d_in[1];
    const float* v        = (const float*)d_in[2];
    const float* W_in     = (const float*)d_in[3];
    const float* b_in     = (const float*)d_in[4];
    const float* rbf_m    = (const float*)d_in[5];
    const float* rbf_b    = (const float*)d_in[6];
    const float* W_e1     = (const float*)d_in[7];
    const float* b_e1     = (const float*)d_in[8];
    const float* W_e2     = (const float*)d_in[9];
    const float* b_e2     = (const float*)d_in[10];
    const float* W_sem    = (const float*)d_in[11];
    const float* b_sem    = (const float*)d_in[12];
    const float* log_g    = (const float*)d_in[13];
    const float* W_xmix   = (const float*)d_in[14];
    const float* W_post1  = (const float*)d_in[15];
    const float* b_post1  = (const float*)d_in[16];
    const float* W_post2  = (const float*)d_in[17];
    const float* b_post2  = (const float*)d_in[18];
    const float* W_node1  = (const float*)d_in[19];
    const float* b_node1  = (const float*)d_in[20];
    const float* W_node2  = (const float*)d_in[21];
    const float* b_node2  = (const float*)d_in[22];
    const float* W_vel1   = (const float*)d_in[23];
    const float* b_vel1   = (const float*)d_in[24];
    const float* W_vel2   = (const float*)d_in[25];
    const float* W_vmix   = (const float*)d_in[26];

    float* out   = (float*)d_out;
    float* out_h = out;
    float* out_x = out + NB * NN * NF;
    float* out_v = out + NB * NN * NF + NB * NN * 3;

    short* wpack = (short*)d_ws;

    pack_weights<<<40, 256, 0, stream>>>(W_e1, W_e2, W_xmix, wpack);

    sake_fused_kernel<<<NB * NN, 256, 0, stream>>>(
        h, x, v, W_in, b_in, rbf_m, rbf_b, b_e1, b_e2,
        W_sem, b_sem, log_g, W_post1, b_post1, W_post2, b_post2,
        W_node1, b_node1, W_node2, b_node2, W_vel1, b_vel1, W_vel2, W_vmix,
        wpack, out_h, out_x, out_v);
}

// Round 3
// 64.415 us; speedup vs baseline: 4.8987x; 1.6020x over previous
//
#include <hip/hip_runtime.h>
#include <math.h>

#define NB 16
#define NN 64
#define NF 64
#define NH 4
#define NR 50
#define NC 256

typedef __attribute__((ext_vector_type(8))) short short8;
typedef __attribute__((ext_vector_type(4))) float f32x4;

// ws layout: wpack (bf16 fragment-major weights) | mid | hagg | comb
#define WS_WE1 0
#define WS_WE2 (1536 * 8)
#define WS_WX  (2048 * 8)
#define MID_F  40960      // float index: 1024 nodes x 128
#define HAGG_F 172032     // 1024 x 256
#define COMB_F 434176     // 1024 x 768

__device__ __forceinline__ float siluf(float x) { return x / (1.f + __expf(-x)); }
__device__ __forceinline__ float tanhfast(float x) { return 1.f - 2.f / (__expf(2.f * x) + 1.f); }

__device__ __forceinline__ ushort f2bf(float f) {
    union { float f; unsigned u; } v; v.f = f;
    unsigned u = v.u;
    return (ushort)((u + 0x7FFFu + ((u >> 16) & 1u)) >> 16);  // RNE
}
__device__ __forceinline__ float bf1(ushort u) {
    union { unsigned u; float f; } c; c.u = ((unsigned)u) << 16; return c.f;
}
__device__ __forceinline__ float bflo(unsigned u) {
    union { unsigned u; float f; } c; c.u = u << 16; return c.f;
}
__device__ __forceinline__ float bfhi(unsigned u) {
    union { unsigned u; float f; } c; c.u = u & 0xFFFF0000u; return c.f;
}

__device__ __forceinline__ float wave_max(float v) {
#pragma unroll
    for (int s = 32; s >= 1; s >>= 1) v = fmaxf(v, __shfl_xor(v, s));
    return v;
}
__device__ __forceinline__ float wave_sum(float v) {
#pragma unroll
    for (int s = 32; s >= 1; s >>= 1) v += __shfl_xor(v, s);
    return v;
}

// ---- prep: pack weights bf16 fragment-major + precompute mid[b,n,:] (i-invariant h_mid parts) ----
__global__ __launch_bounds__(256)
void prep_kernel(const float* __restrict__ W_e1, const float* __restrict__ W_e2,
                 const float* __restrict__ W_xmix,
                 const float* __restrict__ h, const float* __restrict__ W_in,
                 const float* __restrict__ b_in,
                 short* __restrict__ wpack, float* __restrict__ mid)
{
    int blk = blockIdx.x, t = threadIdx.x;
    if (blk < 40) {
        int s = blk * 256 + t;   // 0..10239
        short8 val;
        if (s < 1536) {               // W_e1: K=192 (179 real), N=64
            int cl = s & 15, g = (s >> 4) & 3, q = s >> 6;
            int ks = q % 6, nt = q / 6;
            int c = nt * 16 + cl, k0 = 32 * ks + 8 * g;
#pragma unroll
            for (int i = 0; i < 8; i++) {
                int k = k0 + i;
                float f = (k < 179) ? W_e1[k * NF + c] : 0.f;
                val[i] = (short)f2bf(f);
            }
            *(short8*)(&wpack[WS_WE1 + s * 8]) = val;
        } else if (s < 2048) {        // W_e2: K=64, N=64
            int u = s - 1536;
            int cl = u & 15, g = (u >> 4) & 3, q = u >> 6;
            int ks = q & 1, nt = q >> 1;
            int c = nt * 16 + cl, k0 = 32 * ks + 8 * g;
#pragma unroll
            for (int i = 0; i < 8; i++) val[i] = (short)f2bf(W_e2[(k0 + i) * NF + c]);
            *(short8*)(&wpack[WS_WE2 + u * 8]) = val;
        } else {                      // W_xmix: K=256, N=256
            int u = s - 2048;
            int cl = u & 15, g = (u >> 4) & 3, q = u >> 6;
            int ks = q & 7, wn = q >> 3;
            int c = (wn >> 2) * 64 + (wn & 3) * 16 + cl, k0 = 32 * ks + 8 * g;
#pragma unroll
            for (int i = 0; i < 8; i++) val[i] = (short)f2bf(W_xmix[(k0 + i) * NC + c]);
            *(short8*)(&wpack[WS_WX + u * 8]) = val;
        }
    } else {
        // mid: node-local halves of h_mid. rr<50: hj part; 64<=rr<114: hi part (+b_in)
        int idx = (blk - 40) * 256 + t;     // 0..131071
        int node = idx >> 7, rr = idx & 127;
        const float* hn = h + node * NF;
        if (rr < 50) {
            float acc = 0.f;
#pragma unroll 8
            for (int k = 0; k < 64; k++) acc += hn[k] * W_in[k * NR + rr];
            mid[node * 128 + rr] = acc;
        } else if (rr >= 64 && rr < 114) {
            int r = rr - 64;
            float acc = b_in[r];
#pragma unroll 8
            for (int k = 0; k < 64; k++) acc += hn[k] * W_in[(64 + k) * NR + r];
            mid[node * 128 + rr] = acc;
        }
    }
}

// ---- main: one block per (b,i); edge model + attention + xmix GEMM ----
__global__ __launch_bounds__(256)
void sake_edge_kernel(
    const float* __restrict__ h, const float* __restrict__ x,
    const float* __restrict__ mid,
    const float* __restrict__ rbf_means, const float* __restrict__ rbf_betas,
    const float* __restrict__ b_e1, const float* __restrict__ b_e2,
    const float* __restrict__ W_sem, const float* __restrict__ b_sem,
    const float* __restrict__ log_gamma,
    const short* __restrict__ wpack,
    float* __restrict__ hagg_g, float* __restrict__ comb_g)
{
    const int bi = blockIdx.x;
    const int b  = bi >> 6;
    const int i  = bi & 63;
    const int t  = threadIdx.x;
    const int w  = t >> 6, l = t & 63, lr = l & 15, lg = l >> 4;

    __shared__ __align__(16) short s_A[24 * 64 * 8];   // 24.0 KiB: A staging (fragment-major)
    __shared__ short s_he[64 * 66];                    // 8.25 KiB: h_e bf16, stride 66
    __shared__ float s_comb[768];
    __shared__ float s_xhat[256];
    __shared__ float s_att[256];
    __shared__ float s_wsem[256];
    __shared__ float s_midi[52];

    const short8* A8  = (const short8*)s_A;
    short8*       A8w = (short8*)s_A;
    const short8* We1p = (const short8*)(wpack + WS_WE1);
    const short8* We2p = (const short8*)(wpack + WS_WE2);
    const short8* Wxp  = (const short8*)(wpack + WS_WX);

    // ---------- P0: small staging ----------
    s_wsem[t] = W_sem[t];
    if (t < 50) s_midi[t] = mid[(b * 64 + i) * 128 + 64 + t];
    if (t < 64) {
        int j = t;
        float dx = x[(b * NN + j) * 3 + 0] - x[(b * NN + i) * 3 + 0];
        float dy = x[(b * NN + j) * 3 + 1] - x[(b * NN + i) * 3 + 1];
        float dz = x[(b * NN + j) * 3 + 2] - x[(b * NN + i) * 3 + 2];
        float d2 = dx * dx + dy * dy + dz * dz;
        float d  = sqrtf(fmaxf(d2, 0.f) + 1e-5f);
        float inv = 1.f / (d + 1e-5f);
        s_xhat[j * 4 + 0] = dx * inv;
        s_xhat[j * 4 + 1] = dy * inv;
        s_xhat[j * 4 + 2] = dz * inv;
        s_xhat[j * 4 + 3] = d;
    }
    __syncthreads();

    // ---------- P1: build A slots: 0..7 h_j | 8..15 h_i | 16..23 rbf*h_mid,d,0 ----------
    {
        int j = t & 63, p = t >> 6;
        const float* hj = h + (b * 64 + j) * NF;
        const float* hi = h + (b * 64 + i) * NF;
#pragma unroll
        for (int q = 0; q < 2; q++) {
            int sl = 2 * p + q;
            short8 vj, vi;
#pragma unroll
            for (int e = 0; e < 8; e++) {
                vj[e] = (short)f2bf(hj[sl * 8 + e]);
                vi[e] = (short)f2bf(hi[sl * 8 + e]);
            }
            A8w[sl * 64 + j] = vj;
            A8w[(8 + sl) * 64 + j] = vi;
        }
        float d = s_xhat[j * 4 + 3];
        float cut = 0.5f * (__cosf(d * 0.6283185307179586f) + 1.f) * (d < 5.f ? 1.f : 0.f);
        float emd = __expf(-d);
        const float* midj = mid + (b * 64 + j) * 128;
#pragma unroll
        for (int q = 0; q < 2; q++) {
            int sl = 16 + 2 * p + q;
            short8 val;
#pragma unroll
            for (int e = 0; e < 8; e++) {
                int r = (sl - 16) * 8 + e;   // 0..63
                float o;
                if (r < 50) {
                    float m = midj[r] + s_midi[r];
                    float df = emd - rbf_means[r];
                    o = cut * __expf(-rbf_betas[r] * df * df) * m;
                } else if (r == 50) o = d;
                else o = 0.f;
                val[e] = (short)f2bf(o);
            }
            A8w[sl * 64 + j] = val;
        }
    }
    __syncthreads();

    // ---------- P2 (MFMA): u = silu(A @ W_e1 + b_e1) -> A slots 0..7 ----------
    {
        f32x4 acc[4];
#pragma unroll
        for (int jt = 0; jt < 4; jt++) { acc[jt][0] = 0.f; acc[jt][1] = 0.f; acc[jt][2] = 0.f; acc[jt][3] = 0.f; }
        for (int ks = 0; ks < 6; ks++) {
            short8 bb = We1p[(w * 6 + ks) * 64 + l];
#pragma unroll
            for (int jt = 0; jt < 4; jt++) {
                short8 aa = A8[(ks * 4 + lg) * 64 + jt * 16 + lr];
                acc[jt] = __builtin_amdgcn_mfma_f32_16x16x32_bf16(aa, bb, acc[jt], 0, 0, 0);
            }
        }
        __syncthreads();
        float be = b_e1[w * 16 + lr];
        int f = w * 16 + lr;
#pragma unroll
        for (int jt = 0; jt < 4; jt++)
#pragma unroll
            for (int r = 0; r < 4; r++) {
                int j = jt * 16 + lg * 4 + r;
                s_A[((f >> 3) * 64 + j) * 8 + (f & 7)] = (short)f2bf(siluf(acc[jt][r] + be));
            }
        __syncthreads();
    }

    // ---------- P3 (MFMA): h_e = u @ W_e2 + b_e2 -> s_he (bf16, stride 66) ----------
    {
        f32x4 acc[4];
#pragma unroll
        for (int jt = 0; jt < 4; jt++) { acc[jt][0] = 0.f; acc[jt][1] = 0.f; acc[jt][2] = 0.f; acc[jt][3] = 0.f; }
#pragma unroll
        for (int ks = 0; ks < 2; ks++) {
            short8 bb = We2p[(w * 2 + ks) * 64 + l];
#pragma unroll
            for (int jt = 0; jt < 4; jt++) {
                short8 aa = A8[(ks * 4 + lg) * 64 + jt * 16 + lr];
                acc[jt] = __builtin_amdgcn_mfma_f32_16x16x32_bf16(aa, bb, acc[jt], 0, 0, 0);
            }
        }
        float be2 = b_e2[w * 16 + lr];
        int f = w * 16 + lr;
#pragma unroll
        for (int jt = 0; jt < 4; jt++)
#pragma unroll
            for (int r = 0; r < 4; r++) {
                int j = jt * 16 + lg * 4 + r;
                s_he[j * 66 + f] = (short)f2bf(acc[jt][r] + be2);
            }
        __syncthreads();
    }

    // ---------- P4: sem/euc softmax over j ----------
    {
        int hh = w, j = l;
        float acc = b_sem[hh];
        const unsigned* hp = (const unsigned*)(s_he + j * 66);
#pragma unroll 8
        for (int q = 0; q < 32; q++) {
            unsigned u = hp[q];
            acc += bflo(u) * s_wsem[(2 * q) * 4 + hh] + bfhi(u) * s_wsem[(2 * q + 1) * 4 + hh];
        }
        float cel = fmaxf(acc, 0.f) + fminf(0.f, 2.f * (__expf(0.5f * acc) - 1.f));
        float diag = (j == i) ? 1e5f : 0.f;
        float slog = cel - diag;
        float m1 = wave_max(slog);
        float e1 = __expf(slog - m1);
        float sem = e1 / wave_sum(e1);
        float gam = __expf(log_gamma[hh]);
        float elog = -(s_xhat[j * 4 + 3] + diag) * gam;
        float m2 = wave_max(elog);
        float e2 = __expf(elog - m2);
        float euc = e2 / wave_sum(e2);
        float a = sem * euc;
        a = a / wave_sum(a);
        s_att[j * 4 + hh] = a;
    }
    __syncthreads();

    // ---------- P5: h_agg -> global (c == t) ----------
    {
        int f = t >> 2, hh = t & 3;
        float acc = 0.f;
#pragma unroll 8
        for (int j = 0; j < 64; j++) acc += bf1((ushort)s_he[j * 66 + f]) * s_att[j * 4 + hh];
        hagg_g[bi * 256 + t] = acc;
    }

    // ---------- P6: xmix GEMM in two K-halves; A region reused ----------
    f32x4 acc[4][4];
#pragma unroll
    for (int jt = 0; jt < 4; jt++)
#pragma unroll
        for (int nt = 0; nt < 4; nt++) { acc[jt][nt][0] = 0.f; acc[jt][nt][1] = 0.f; acc[jt][nt][2] = 0.f; acc[jt][nt][3] = 0.f; }

    for (int half = 0; half < 2; half++) {
        {   // build hea slots 0..15 for k in [128*half, 128*half+128)
            int j = t & 63, kc = t >> 6;
            float a0 = s_att[j * 4 + 0], a1 = s_att[j * 4 + 1];
            float a2 = s_att[j * 4 + 2], a3 = s_att[j * 4 + 3];
#pragma unroll
            for (int s = 0; s < 4; s++) {
                int sl = kc * 4 + s;
                int kbase = half * 128 + sl * 8;
                unsigned u = *(const unsigned*)(s_he + j * 66 + (kbase >> 2));
                float h0 = bflo(u), h1 = bfhi(u);
                short8 val;
                val[0] = (short)f2bf(h0 * a0); val[1] = (short)f2bf(h0 * a1);
                val[2] = (short)f2bf(h0 * a2); val[3] = (short)f2bf(h0 * a3);
                val[4] = (short)f2bf(h1 * a0); val[5] = (short)f2bf(h1 * a1);
                val[6] = (short)f2bf(h1 * a2); val[7] = (short)f2bf(h1 * a3);
                A8w[sl * 64 + j] = val;
            }
        }
        __syncthreads();
#pragma unroll
        for (int ks = 0; ks < 4; ks++) {
            short8 aa[4], bb[4];
#pragma unroll
            for (int jt = 0; jt < 4; jt++) aa[jt] = A8[(ks * 4 + lg) * 64 + jt * 16 + lr];
#pragma unroll
            for (int nt = 0; nt < 4; nt++) bb[nt] = Wxp[((w * 4 + nt) * 8 + half * 4 + ks) * 64 + l];
#pragma unroll
            for (int jt = 0; jt < 4; jt++)
#pragma unroll
                for (int nt = 0; nt < 4; nt++)
                    acc[jt][nt] = __builtin_amdgcn_mfma_f32_16x16x32_bf16(aa[jt], bb[nt], acc[jt][nt], 0, 0, 0);
        }
        __syncthreads();
    }

    // epilogue: tanh, weight by x_hat, reduce over j -> comb_sum (mean)
    {
#pragma unroll
        for (int nt = 0; nt < 4; nt++) {
            float p0 = 0.f, p1 = 0.f, p2 = 0.f;
#pragma unroll
            for (int jt = 0; jt < 4; jt++)
#pragma unroll
                for (int r = 0; r < 4; r++) {
                    int j = jt * 16 + lg * 4 + r;
                    float th = tanhfast(acc[jt][nt][r]);
                    p0 += s_xhat[j * 4 + 0] * th;
                    p1 += s_xhat[j * 4 + 1] * th;
                    p2 += s_xhat[j * 4 + 2] * th;
                }
            p0 += __shfl_xor(p0, 16); p0 += __shfl_xor(p0, 32);
            p1 += __shfl_xor(p1, 16); p1 += __shfl_xor(p1, 32);
            p2 += __shfl_xor(p2, 16); p2 += __shfl_xor(p2, 32);
            if (lg == 0) {
                int c = w * 64 + nt * 16 + lr;
                s_comb[c * 3 + 0] = p0 * (1.f / 64.f);
                s_comb[c * 3 + 1] = p1 * (1.f / 64.f);
                s_comb[c * 3 + 2] = p2 * (1.f / 64.f);
            }
        }
    }
    __syncthreads();
    {
        float* cg = comb_g + bi * 768;
        cg[t] = s_comb[t];
        cg[256 + t] = s_comb[256 + t];
        cg[512 + t] = s_comb[512 + t];
    }
}

// ---- tail: per-node MLPs; one wave per node, 4 nodes per block ----
__global__ __launch_bounds__(256)
void sake_tail_kernel(
    const float* __restrict__ h, const float* __restrict__ x, const float* __restrict__ v,
    const float* __restrict__ hagg_g, const float* __restrict__ comb_g,
    const float* __restrict__ W_post1, const float* __restrict__ b_post1,
    const float* __restrict__ W_post2, const float* __restrict__ b_post2,
    const float* __restrict__ W_node1, const float* __restrict__ b_node1,
    const float* __restrict__ W_node2, const float* __restrict__ b_node2,
    const float* __restrict__ W_vel1, const float* __restrict__ b_vel1,
    const float* __restrict__ W_vel2, const float* __restrict__ W_vmix,
    float* __restrict__ out_h, float* __restrict__ out_x, float* __restrict__ out_v)
{
    const int t = threadIdx.x, r = t >> 6, l = t & 63;
    const int node = blockIdx.x * 4 + r;

    __shared__ float s_in[4][384];    // [h_i | hagg | h_comb]
    __shared__ float s_hcp[4][256];
    __shared__ float s_p1[4][64];
    __shared__ float s_ho[4][64];

    float cmb[4][3];
#pragma unroll
    for (int q = 0; q < 4; q++) {
        int c = q * 64 + l;
        float c0 = comb_g[node * 768 + c * 3 + 0];
        float c1 = comb_g[node * 768 + c * 3 + 1];
        float c2 = comb_g[node * 768 + c * 3 + 2];
        cmb[q][0] = c0; cmb[q][1] = c1; cmb[q][2] = c2;
        s_hcp[r][c] = c0 * c0 + c1 * c1 + c2 * c2;
    }
    float hi = h[node * NF + l];
    s_in[r][l] = hi;
#pragma unroll
    for (int q = 0; q < 4; q++) s_in[r][64 + q * 64 + l] = hagg_g[node * 256 + q * 64 + l];
    __syncthreads();

    float a1 = b_post1[l];
#pragma unroll 8
    for (int c = 0; c < 256; c++) a1 += s_hcp[r][c] * W_post1[c * NF + l];
    s_p1[r][l] = siluf(a1);
    __syncthreads();

    float a2 = b_post2[l];
#pragma unroll 8
    for (int k = 0; k < 64; k++) a2 += s_p1[r][k] * W_post2[k * NF + l];
    s_in[r][320 + l] = siluf(a2);
    __syncthreads();

    float a3 = b_node1[l];
#pragma unroll 8
    for (int k = 0; k < 384; k++) a3 += s_in[r][k] * W_node1[k * NF + l];
    s_p1[r][l] = siluf(a3);
    __syncthreads();

    float a4 = b_node2[l];
#pragma unroll 8
    for (int k = 0; k < 64; k++) a4 += s_p1[r][k] * W_node2[k * NF + l];
    float ho = hi + siluf(a4);
    out_h[node * NF + l] = ho;
    s_ho[r][l] = ho;
    __syncthreads();

    float a5 = b_vel1[l];
#pragma unroll 8
    for (int k = 0; k < 64; k++) a5 += s_ho[r][k] * W_vel1[k * NF + l];
    float g = wave_sum(siluf(a5) * W_vel2[l]);
    g = 2.f / (1.f + __expf(-g));

    float dv[3];
#pragma unroll
    for (int k = 0; k < 3; k++) {
        float p = 0.f;
#pragma unroll
        for (int q = 0; q < 4; q++) p += cmb[q][k] * W_vmix[q * 64 + l];
        dv[k] = wave_sum(p);
    }
    if (l < 3) {
        float vout = dv[l] + g * v[node * 3 + l];
        out_v[node * 3 + l] = vout;
        out_x[node * 3 + l] = x[node * 3 + l] + vout;
    }
}

extern "C" void kernel_launch(void* const* d_in, const int* in_sizes, int n_in,
                              void* d_out, int out_size, void* d_ws, size_t ws_size,
                              hipStream_t stream) {
    const float* h        = (const float*)d_in[0];
    const float* x        = (const float*)d_in[1];
    const float* v        = (const float*)d_in[2];
    const float* W_in     = (const float*)d_in[3];
    const float* b_in     = (const float*)d_in[4];
    const float* rbf_m    = (const float*)d_in[5];
    const float* rbf_b    = (const float*)d_in[6];
    const float* W_e1     = (const float*)d_in[7];
    const float* b_e1     = (const float*)d_in[8];
    const float* W_e2     = (const float*)d_in[9];
    const float* b_e2     = (const float*)d_in[10];
    const float* W_sem    = (const float*)d_in[11];
    const float* b_sem    = (const float*)d_in[12];
    const float* log_g    = (const float*)d_in[13];
    const float* W_xmix   = (const float*)d_in[14];
    const float* W_post1  = (const float*)d_in[15];
    const float* b_post1  = (const float*)d_in[16];
    const float* W_post2  = (const float*)d_in[17];
    const float* b_post2  = (const float*)d_in[18];
    const float* W_node1  = (const float*)d_in[19];
    const float* b_node1  = (const float*)d_in[20];
    const float* W_node2  = (const float*)d_in[21];
    const float* b_node2  = (const float*)d_in[22];
    const float* W_vel1   = (const float*)d_in[23];
    const float* b_vel1   = (const float*)d_in[24];
    const float* W_vel2   = (const float*)d_in[25];
    const float* W_vmix   = (const float*)d_in[26];

    float* out   = (float*)d_out;
    float* out_h = out;
    float* out_x = out + NB * NN * NF;
    float* out_v = out + NB * NN * NF + NB * NN * 3;

    short* wpack = (short*)d_ws;
    float* wsf   = (float*)d_ws;
    float* mid   = wsf + MID_F;
    float* hagg  = wsf + HAGG_F;
    float* comb  = wsf + COMB_F;

    prep_kernel<<<552, 256, 0, stream>>>(W_e1, W_e2, W_xmix, h, W_in, b_in, wpack, mid);

    sake_edge_kernel<<<NB * NN, 256, 0, stream>>>(
        h, x, mid, rbf_m, rbf_b, b_e1, b_e2, W_sem, b_sem, log_g,
        wpack, hagg, comb);

    sake_tail_kernel<<<256, 256, 0, stream>>>(
        h, x, v, hagg, comb,
        W_post1, b_post1, W_post2, b_post2, W_node1, b_node1, W_node2, b_node2,
        W_vel1, b_vel1, W_vel2, W_vmix, out_h, out_x, out_v);
}

// Round 4
// 56.049 us; speedup vs baseline: 5.6299x; 1.1493x over previous
//
#include <hip/hip_runtime.h>
#include <math.h>

#define NB 16
#define NN 64
#define NF 64
#define NH 4
#define NR 50
#define NC 256

typedef __attribute__((ext_vector_type(8))) short short8;
typedef __attribute__((ext_vector_type(4))) float f32x4;

// ws layout (shorts): We1rbf (512 slots) | We2 (512) | Wx (8192); then floats: mid | e1 | hagg | comb
#define WS_WE1R 0
#define WS_WE2  4096
#define WS_WX   8192
#define MID_F   36864                  // 1024 nodes x 128 (midj | midi)
#define E1_F    (MID_F + 131072)       // 1024 x 128 (E1j | E1i+b)
#define HAGG_F  (E1_F + 131072)        // 1024 x 256
#define COMB_F  (HAGG_F + 262144)      // 1024 x 768

__device__ __forceinline__ float siluf(float x) { return x / (1.f + __expf(-x)); }
__device__ __forceinline__ float tanhfast(float x) { return 1.f - 2.f / (__expf(2.f * x) + 1.f); }

__device__ __forceinline__ short f2bfs(float f) {
    __bf16 b = (__bf16)f;                       // compiler emits v_cvt_pk_bf16_f32 (RNE)
    union { __bf16 b; short s; } u; u.b = b; return u.s;
}
__device__ __forceinline__ float bf1(ushort u) {
    union { unsigned u; float f; } c; c.u = ((unsigned)u) << 16; return c.f;
}
__device__ __forceinline__ float bflo(unsigned u) {
    union { unsigned u; float f; } c; c.u = u << 16; return c.f;
}
__device__ __forceinline__ float bfhi(unsigned u) {
    union { unsigned u; float f; } c; c.u = u & 0xFFFF0000u; return c.f;
}

__device__ __forceinline__ float wave_max(float v) {
#pragma unroll
    for (int s = 32; s >= 1; s >>= 1) v = fmaxf(v, __shfl_xor(v, s));
    return v;
}
__device__ __forceinline__ float wave_sum(float v) {
#pragma unroll
    for (int s = 32; s >= 1; s >>= 1) v += __shfl_xor(v, s);
    return v;
}

// ---- prep: pack weights bf16 fragment-major + per-node precomputes (mid, E1) ----
__global__ __launch_bounds__(256)
void prep_kernel(const float* __restrict__ W_e1, const float* __restrict__ b_e1,
                 const float* __restrict__ W_e2, const float* __restrict__ W_xmix,
                 const float* __restrict__ h, const float* __restrict__ W_in,
                 const float* __restrict__ b_in,
                 short* __restrict__ wpack, float* __restrict__ mid, float* __restrict__ e1)
{
    int blk = blockIdx.x, t = threadIdx.x;
    if (blk < 36) {
        int s = blk * 256 + t;   // 0..9215
        short8 val;
        if (s < 512) {                // W_e1 rbf part: K=64 (50 rbf + d), N=64
            int cl = s & 15, g = (s >> 4) & 3, q = s >> 6;
            int ks = q & 1, nt = q >> 1;
            int c = nt * 16 + cl, k0 = 32 * ks + 8 * g;
#pragma unroll
            for (int i = 0; i < 8; i++) {
                int kr = k0 + i;
                float f = (kr < 50) ? W_e1[(128 + kr) * NF + c] : (kr == 50 ? W_e1[178 * NF + c] : 0.f);
                val[i] = f2bfs(f);
            }
            *(short8*)(&wpack[WS_WE1R + s * 8]) = val;
        } else if (s < 1024) {        // W_e2: K=64, N=64
            int u = s - 512;
            int cl = u & 15, g = (u >> 4) & 3, q = u >> 6;
            int ks = q & 1, nt = q >> 1;
            int c = nt * 16 + cl, k0 = 32 * ks + 8 * g;
#pragma unroll
            for (int i = 0; i < 8; i++) val[i] = f2bfs(W_e2[(k0 + i) * NF + c]);
            *(short8*)(&wpack[WS_WE2 + u * 8]) = val;
        } else {                      // W_xmix: K=256, N=256
            int u = s - 1024;
            int cl = u & 15, g = (u >> 4) & 3, q = u >> 6;
            int ks = q & 7, wn = q >> 3;
            int c = (wn >> 2) * 64 + (wn & 3) * 16 + cl, k0 = 32 * ks + 8 * g;
#pragma unroll
            for (int i = 0; i < 8; i++) val[i] = f2bfs(W_xmix[(k0 + i) * NC + c]);
            *(short8*)(&wpack[WS_WX + u * 8]) = val;
        }
    } else {
        // per-node precompute: node = blk-36; h row staged in LDS
        int node = blk - 36;
        __shared__ float s_hn[64];
        if (t < 64) s_hn[t] = h[node * NF + t];
        __syncthreads();
        if (t < 64) {                    // E1j[f] = h . W_e1[0:64, f]
            float acc = 0.f;
#pragma unroll 8
            for (int k = 0; k < 64; k++) acc += s_hn[k] * W_e1[k * NF + t];
            e1[node * 128 + t] = acc;
        } else if (t < 128) {            // E1i[f] = h . W_e1[64:128, f] + b_e1
            int f = t - 64;
            float acc = b_e1[f];
#pragma unroll 8
            for (int k = 0; k < 64; k++) acc += s_hn[k] * W_e1[(64 + k) * NF + f];
            e1[node * 128 + 64 + f] = acc;
        } else if (t < 178) {            // midj[r]
            int r = t - 128;
            float acc = 0.f;
#pragma unroll 8
            for (int k = 0; k < 64; k++) acc += s_hn[k] * W_in[k * NR + r];
            mid[node * 128 + r] = acc;
        } else if (t >= 192 && t < 242) { // midi[r] (+b_in)
            int r = t - 192;
            float acc = b_in[r];
#pragma unroll 8
            for (int k = 0; k < 64; k++) acc += s_hn[k] * W_in[(64 + k) * NR + r];
            mid[node * 128 + 64 + r] = acc;
        }
    }
}

// ---- main: one block per (b,i); edge model + attention + xmix GEMM ----
__global__ __launch_bounds__(256)
void sake_edge_kernel(
    const float* __restrict__ x,
    const float* __restrict__ mid, const float* __restrict__ e1,
    const float* __restrict__ rbf_means, const float* __restrict__ rbf_betas,
    const float* __restrict__ b_e2,
    const float* __restrict__ W_sem, const float* __restrict__ b_sem,
    const float* __restrict__ log_gamma,
    const short* __restrict__ wpack,
    float* __restrict__ hagg_g, float* __restrict__ comb_g)
{
    const int bi = blockIdx.x;
    const int b  = bi >> 6;
    const int i  = bi & 63;
    const int t  = threadIdx.x;
    const int w  = t >> 6, l = t & 63, lr = l & 15, lg = l >> 4;

    __shared__ __align__(16) short s_A[16 * 64 * 8];   // 16 KiB A staging (fragment-major)
    __shared__ short s_he[64 * 66];                    // 8.25 KiB h_e bf16
    __shared__ float s_xhat[256];
    __shared__ float s_att[256];
    __shared__ float s_wsem[256];
    __shared__ float s_midi[52];

    const short8* A8  = (const short8*)s_A;
    short8*       A8w = (short8*)s_A;
    const short8* We1p = (const short8*)(wpack + WS_WE1R);
    const short8* We2p = (const short8*)(wpack + WS_WE2);
    const short8* Wxp  = (const short8*)(wpack + WS_WX);

    // ---------- P0: small staging ----------
    s_wsem[t] = W_sem[t];
    if (t < 50) s_midi[t] = mid[(b * 64 + i) * 128 + 64 + t];
    if (t < 64) {
        int j = t;
        float dx = x[(b * NN + j) * 3 + 0] - x[(b * NN + i) * 3 + 0];
        float dy = x[(b * NN + j) * 3 + 1] - x[(b * NN + i) * 3 + 1];
        float dz = x[(b * NN + j) * 3 + 2] - x[(b * NN + i) * 3 + 2];
        float d2 = dx * dx + dy * dy + dz * dz;
        float d  = sqrtf(fmaxf(d2, 0.f) + 1e-5f);
        float inv = 1.f / (d + 1e-5f);
        s_xhat[j * 4 + 0] = dx * inv;
        s_xhat[j * 4 + 1] = dy * inv;
        s_xhat[j * 4 + 2] = dz * inv;
        s_xhat[j * 4 + 3] = d;
    }
    __syncthreads();

    // ---------- P1: build rbf A slots 0..7 (K=64: 50 rbf | d | 0) ----------
    {
        int j = t & 63, p = t >> 6;
        float d = s_xhat[j * 4 + 3];
        float cut = 0.5f * (__cosf(d * 0.6283185307179586f) + 1.f) * (d < 5.f ? 1.f : 0.f);
        float emd = __expf(-d);
        const float* midj = mid + (b * 64 + j) * 128;
#pragma unroll
        for (int q = 0; q < 2; q++) {
            int sl = 2 * p + q;
            short8 val;
#pragma unroll
            for (int e = 0; e < 8; e++) {
                int r = sl * 8 + e;
                float o;
                if (r < 50) {
                    float m = midj[r] + s_midi[r];
                    float df = emd - rbf_means[r];
                    o = cut * __expf(-rbf_betas[r] * df * df) * m;
                } else if (r == 50) o = d;
                else o = 0.f;
                val[e] = f2bfs(o);
            }
            A8w[sl * 64 + j] = val;
        }
    }
    __syncthreads();

    // ---------- P2 (MFMA, K=64, C-init = E1j+E1i): u = silu(...) -> A slots 0..7 ----------
    {
        int f = w * 16 + lr;
        const float* e1b = e1 + (size_t)b * 64 * 128;
        float e1i_v = e1b[i * 128 + 64 + f];
        f32x4 acc[4];
#pragma unroll
        for (int jt = 0; jt < 4; jt++)
#pragma unroll
            for (int r = 0; r < 4; r++) {
                int j = jt * 16 + lg * 4 + r;
                acc[jt][r] = e1b[j * 128 + f] + e1i_v;
            }
#pragma unroll
        for (int ks = 0; ks < 2; ks++) {
            short8 bb = We1p[(w * 2 + ks) * 64 + l];
#pragma unroll
            for (int jt = 0; jt < 4; jt++) {
                short8 aa = A8[(ks * 4 + lg) * 64 + jt * 16 + lr];
                acc[jt] = __builtin_amdgcn_mfma_f32_16x16x32_bf16(aa, bb, acc[jt], 0, 0, 0);
            }
        }
        __syncthreads();   // all rbf-A reads done before overwrite with u
#pragma unroll
        for (int jt = 0; jt < 4; jt++)
#pragma unroll
            for (int r = 0; r < 4; r++) {
                int j = jt * 16 + lg * 4 + r;
                s_A[((f >> 3) * 64 + j) * 8 + (f & 7)] = f2bfs(siluf(acc[jt][r]));
            }
        __syncthreads();
    }

    // ---------- P3 (MFMA): h_e = u @ W_e2 + b_e2 -> s_he (bf16) ----------
    {
        f32x4 acc[4];
#pragma unroll
        for (int jt = 0; jt < 4; jt++) { acc[jt][0] = 0.f; acc[jt][1] = 0.f; acc[jt][2] = 0.f; acc[jt][3] = 0.f; }
#pragma unroll
        for (int ks = 0; ks < 2; ks++) {
            short8 bb = We2p[(w * 2 + ks) * 64 + l];
#pragma unroll
            for (int jt = 0; jt < 4; jt++) {
                short8 aa = A8[(ks * 4 + lg) * 64 + jt * 16 + lr];
                acc[jt] = __builtin_amdgcn_mfma_f32_16x16x32_bf16(aa, bb, acc[jt], 0, 0, 0);
            }
        }
        float be2 = b_e2[w * 16 + lr];
        int f = w * 16 + lr;
#pragma unroll
        for (int jt = 0; jt < 4; jt++)
#pragma unroll
            for (int r = 0; r < 4; r++) {
                int j = jt * 16 + lg * 4 + r;
                s_he[j * 66 + f] = f2bfs(acc[jt][r] + be2);
            }
        __syncthreads();
    }

    // ---------- P4: sem/euc softmax over j ----------
    {
        int hh = w, j = l;
        float acc = b_sem[hh];
        const unsigned* hp = (const unsigned*)(s_he + j * 66);
#pragma unroll 8
        for (int q = 0; q < 32; q++) {
            unsigned u = hp[q];
            acc += bflo(u) * s_wsem[(2 * q) * 4 + hh] + bfhi(u) * s_wsem[(2 * q + 1) * 4 + hh];
        }
        float cel = fmaxf(acc, 0.f) + fminf(0.f, 2.f * (__expf(0.5f * acc) - 1.f));
        float diag = (j == i) ? 1e5f : 0.f;
        float slog = cel - diag;
        float m1 = wave_max(slog);
        float e1v = __expf(slog - m1);
        float sem = e1v / wave_sum(e1v);
        float gam = __expf(log_gamma[hh]);
        float elog = -(s_xhat[j * 4 + 3] + diag) * gam;
        float m2 = wave_max(elog);
        float e2 = __expf(elog - m2);
        float euc = e2 / wave_sum(e2);
        float a = sem * euc;
        a = a / wave_sum(a);
        s_att[j * 4 + hh] = a;
    }
    __syncthreads();

    // ---------- P5: h_agg -> global (c == t) ----------
    {
        int f = t >> 2, hh = t & 3;
        float acc = 0.f;
#pragma unroll 8
        for (int j = 0; j < 64; j++) acc += bf1((ushort)s_he[j * 66 + f]) * s_att[j * 4 + hh];
        hagg_g[bi * 256 + t] = acc;
    }

    // ---------- P6: xmix GEMM in two K-halves ----------
    f32x4 acc[4][4];
#pragma unroll
    for (int jt = 0; jt < 4; jt++)
#pragma unroll
        for (int nt = 0; nt < 4; nt++) { acc[jt][nt][0] = 0.f; acc[jt][nt][1] = 0.f; acc[jt][nt][2] = 0.f; acc[jt][nt][3] = 0.f; }

    for (int half = 0; half < 2; half++) {
        {   // build hea slots 0..15 for k in [128*half, +128)
            int j = t & 63, kc = t >> 6;
            float a0 = s_att[j * 4 + 0], a1 = s_att[j * 4 + 1];
            float a2 = s_att[j * 4 + 2], a3 = s_att[j * 4 + 3];
#pragma unroll
            for (int s = 0; s < 4; s++) {
                int sl = kc * 4 + s;
                int kbase = half * 128 + sl * 8;
                unsigned u = *(const unsigned*)(s_he + j * 66 + (kbase >> 2));
                float h0 = bflo(u), h1 = bfhi(u);
                short8 val;
                val[0] = f2bfs(h0 * a0); val[1] = f2bfs(h0 * a1);
                val[2] = f2bfs(h0 * a2); val[3] = f2bfs(h0 * a3);
                val[4] = f2bfs(h1 * a0); val[5] = f2bfs(h1 * a1);
                val[6] = f2bfs(h1 * a2); val[7] = f2bfs(h1 * a3);
                A8w[sl * 64 + j] = val;
            }
        }
        __syncthreads();
#pragma unroll
        for (int ks = 0; ks < 4; ks++) {
            short8 aa[4], bb[4];
#pragma unroll
            for (int jt = 0; jt < 4; jt++) aa[jt] = A8[(ks * 4 + lg) * 64 + jt * 16 + lr];
#pragma unroll
            for (int nt = 0; nt < 4; nt++) bb[nt] = Wxp[((w * 4 + nt) * 8 + half * 4 + ks) * 64 + l];
#pragma unroll
            for (int jt = 0; jt < 4; jt++)
#pragma unroll
                for (int nt = 0; nt < 4; nt++)
                    acc[jt][nt] = __builtin_amdgcn_mfma_f32_16x16x32_bf16(aa[jt], bb[nt], acc[jt][nt], 0, 0, 0);
        }
        __syncthreads();
    }

    // epilogue: tanh, weight by x_hat, reduce over j -> comb (mean), direct to global
    {
#pragma unroll
        for (int nt = 0; nt < 4; nt++) {
            float p0 = 0.f, p1 = 0.f, p2 = 0.f;
#pragma unroll
            for (int jt = 0; jt < 4; jt++)
#pragma unroll
                for (int r = 0; r < 4; r++) {
                    int j = jt * 16 + lg * 4 + r;
                    float th = tanhfast(acc[jt][nt][r]);
                    p0 += s_xhat[j * 4 + 0] * th;
                    p1 += s_xhat[j * 4 + 1] * th;
                    p2 += s_xhat[j * 4 + 2] * th;
                }
            p0 += __shfl_xor(p0, 16); p0 += __shfl_xor(p0, 32);
            p1 += __shfl_xor(p1, 16); p1 += __shfl_xor(p1, 32);
            p2 += __shfl_xor(p2, 16); p2 += __shfl_xor(p2, 32);
            if (lg == 0) {
                int c = w * 64 + nt * 16 + lr;
                float* cg = comb_g + bi * 768 + c * 3;
                cg[0] = p0 * (1.f / 64.f);
                cg[1] = p1 * (1.f / 64.f);
                cg[2] = p2 * (1.f / 64.f);
            }
        }
    }
}

// ---- tail: per-node MLPs; ONE node per block, K-loops split across 4 waves ----
__global__ __launch_bounds__(256)
void sake_tail_kernel(
    const float* __restrict__ h, const float* __restrict__ x, const float* __restrict__ v,
    const float* __restrict__ hagg_g, const float* __restrict__ comb_g,
    const float* __restrict__ W_post1, const float* __restrict__ b_post1,
    const float* __restrict__ W_post2, const float* __restrict__ b_post2,
    const float* __restrict__ W_node1, const float* __restrict__ b_node1,
    const float* __restrict__ W_node2, const float* __restrict__ b_node2,
    const float* __restrict__ W_vel1, const float* __restrict__ b_vel1,
    const float* __restrict__ W_vel2, const float* __restrict__ W_vmix,
    float* __restrict__ out_h, float* __restrict__ out_x, float* __restrict__ out_v)
{
    const int node = blockIdx.x;
    const int t = threadIdx.x, w = t >> 6, l = t & 63;

    __shared__ float s_in[384];      // [h | hagg | hcomb]
    __shared__ float s_hcp[256];
    __shared__ float s_cmb[3][256];
    __shared__ float s_red[4][64];
    __shared__ float s_vec[64];
    __shared__ float s_ho[64];

    {
        const float* cg = comb_g + node * 768;
        float c0 = cg[t * 3 + 0], c1 = cg[t * 3 + 1], c2 = cg[t * 3 + 2];
        s_cmb[0][t] = c0; s_cmb[1][t] = c1; s_cmb[2][t] = c2;
        s_hcp[t] = c0 * c0 + c1 * c1 + c2 * c2;
        if (t < 64) s_in[t] = h[node * NF + t];
        s_in[64 + t] = hagg_g[node * 256 + t];
    }
    __syncthreads();

    // post1: K=256, 64 k's per wave
    {
        float p = 0.f;
#pragma unroll 8
        for (int k = w * 64; k < w * 64 + 64; k++) p += s_hcp[k] * W_post1[k * NF + l];
        s_red[w][l] = p;
    }
    __syncthreads();
    {
        float a = b_post1[l] + s_red[0][l] + s_red[1][l] + s_red[2][l] + s_red[3][l];
        if (w == 0) s_vec[l] = siluf(a);
    }
    __syncthreads();

    // post2: K=64, 16 per wave -> h_comb
    {
        float p = 0.f;
#pragma unroll
        for (int k = w * 16; k < w * 16 + 16; k++) p += s_vec[k] * W_post2[k * NF + l];
        s_red[w][l] = p;
    }
    __syncthreads();
    {
        float a = b_post2[l] + s_red[0][l] + s_red[1][l] + s_red[2][l] + s_red[3][l];
        if (w == 0) s_in[320 + l] = siluf(a);
    }
    __syncthreads();

    // node1: K=384, 96 per wave
    {
        float p = 0.f;
#pragma unroll 8
        for (int k = w * 96; k < w * 96 + 96; k++) p += s_in[k] * W_node1[k * NF + l];
        s_red[w][l] = p;
    }
    __syncthreads();
    {
        float a = b_node1[l] + s_red[0][l] + s_red[1][l] + s_red[2][l] + s_red[3][l];
        if (w == 0) s_vec[l] = siluf(a);
    }
    __syncthreads();

    // node2 + residual -> h_out
    {
        float p = 0.f;
#pragma unroll
        for (int k = w * 16; k < w * 16 + 16; k++) p += s_vec[k] * W_node2[k * NF + l];
        s_red[w][l] = p;
    }
    __syncthreads();
    {
        float a = b_node2[l] + s_red[0][l] + s_red[1][l] + s_red[2][l] + s_red[3][l];
        float ho = s_in[l] + siluf(a);
        if (w == 0) { out_h[node * NF + l] = ho; s_ho[l] = ho; }
    }
    __syncthreads();

    // vel1
    {
        float p = 0.f;
#pragma unroll
        for (int k = w * 16; k < w * 16 + 16; k++) p += s_ho[k] * W_vel1[k * NF + l];
        s_red[w][l] = p;
    }
    __syncthreads();
    {
        float a = b_vel1[l] + s_red[0][l] + s_red[1][l] + s_red[2][l] + s_red[3][l];
        float v1 = siluf(a);
        float g = wave_sum(v1 * W_vel2[l]);
        g = 2.f / (1.f + __expf(-g));
        if (w < 3) {
            float pv = 0.f;
#pragma unroll
            for (int q = 0; q < 4; q++) pv += s_cmb[w][q * 64 + l] * W_vmix[q * 64 + l];
            float dv = wave_sum(pv);
            if (l == 0) {
                float vout = dv + g * v[node * 3 + w];
                out_v[node * 3 + w] = vout;
                out_x[node * 3 + w] = x[node * 3 + w] + vout;
            }
        }
    }
}

extern "C" void kernel_launch(void* const* d_in, const int* in_sizes, int n_in,
                              void* d_out, int out_size, void* d_ws, size_t ws_size,
                              hipStream_t stream) {
    const float* h        = (const float*)d_in[0];
    const float* x        = (const float*)d_in[1];
    const float* v        = (const float*)d_in[2];
    const float* W_in     = (const float*)d_in[3];
    const float* b_in     = (const float*)d_in[4];
    const float* rbf_m    = (const float*)d_in[5];
    const float* rbf_b    = (const float*)d_in[6];
    const float* W_e1     = (const float*)d_in[7];
    const float* b_e1     = (const float*)d_in[8];
    const float* W_e2     = (const float*)d_in[9];
    const float* b_e2     = (const float*)d_in[10];
    const float* W_sem    = (const float*)d_in[11];
    const float* b_sem    = (const float*)d_in[12];
    const float* log_g    = (const float*)d_in[13];
    const float* W_xmix   = (const float*)d_in[14];
    const float* W_post1  = (const float*)d_in[15];
    const float* b_post1  = (const float*)d_in[16];
    const float* W_post2  = (const float*)d_in[17];
    const float* b_post2  = (const float*)d_in[18];
    const float* W_node1  = (const float*)d_in[19];
    const float* b_node1  = (const float*)d_in[20];
    const float* W_node2  = (const float*)d_in[21];
    const float* b_node2  = (const float*)d_in[22];
    const float* W_vel1   = (const float*)d_in[23];
    const float* b_vel1   = (const float*)d_in[24];
    const float* W_vel2   = (const float*)d_in[25];
    const float* W_vmix   = (const float*)d_in[26];

    float* out   = (float*)d_out;
    float* out_h = out;
    float* out_x = out + NB * NN * NF;
    float* out_v = out + NB * NN * NF + NB * NN * 3;

    short* wpack = (short*)d_ws;
    float* wsf   = (float*)d_ws;
    float* mid   = wsf + MID_F;
    float* e1    = wsf + E1_F;
    float* hagg  = wsf + HAGG_F;
    float* comb  = wsf + COMB_F;

    prep_kernel<<<36 + 1024, 256, 0, stream>>>(W_e1, b_e1, W_e2, W_xmix, h, W_in, b_in,
                                               wpack, mid, e1);

    sake_edge_kernel<<<NB * NN, 256, 0, stream>>>(
        x, mid, e1, rbf_m, rbf_b, b_e2, W_sem, b_sem, log_g,
        wpack, hagg, comb);

    sake_tail_kernel<<<1024, 256, 0, stream>>>(
        h, x, v, hagg, comb,
        W_post1, b_post1, W_post2, b_post2, W_node1, b_node1, W_node2, b_node2,
        W_vel1, b_vel1, W_vel2, W_vmix, out_h, out_x, out_v);
}